// Round 10
// baseline (108.417 us; speedup 1.0000x reference)
//
#include <hip/hip_runtime.h>

#define C_IN   64
#define HW_DIM 64
#define C_OUT  128
#define NG     8
#define KSPL   4608     // 576 * 8
#define BM     32       // pixels per block (half an image row)
#define NSPL_STEPS 72   // KSPL / 64
#define NSTEPS 81
#define NPAD   66
#define NEXP   (8 * C_IN * NPAD * NPAD)   // 2,230,272 padded elements

// d_ws layout (bytes)
#define WT_BYTES 1327104                  // 81*128*64*2
#define XE_OFF   WT_BYTES
#define XE_BYTES (NEXP * NG * 2)          // 35,684,352
#define SE_OFF   (XE_OFF + XE_BYTES)

typedef __attribute__((ext_vector_type(8))) __bf16 bf16x8;
typedef __attribute__((ext_vector_type(4))) float  f32x4;

// --------------------------------------------------------------------------
// Weight prep: pack spline_w ++ base_w into per-co-quarter MFMA-fragment
// order: wt3[step][cq(4)][n(2)][ks(2)][lane(64)][8], value = W[co][k],
// co = cq*32 + n*16 + (lane&15), k = step*64 + ks*32 + (lane>>4)*8 + e.
// --------------------------------------------------------------------------
__global__ __launch_bounds__(256)
void prep_wt(const float* __restrict__ sw, const float* __restrict__ bw,
             __bf16* __restrict__ wt3)
{
  const int step = blockIdx.x;
  const int t    = threadIdx.x;
  const int cq   = t >> 6;
  const int lane = t & 63;
  const int l15  = lane & 15;
  const int g4   = lane >> 4;
#pragma unroll
  for (int n = 0; n < 2; ++n)
#pragma unroll
    for (int ks = 0; ks < 2; ++ks) {
      const int co = cq * 32 + n * 16 + l15;
      bf16x8 v;
#pragma unroll
      for (int e = 0; e < 8; ++e) {
        const int k = step * 64 + ks * 32 + g4 * 8 + e;
        float f;
        if (k < KSPL) f = sw[(size_t)k * C_OUT + co];
        else          f = bw[(size_t)(k - KSPL) * C_OUT + co];
        v[e] = (__bf16)f;
      }
      *(bf16x8*)(wt3 + (size_t)step * 8192 + cq * 2048 + (n * 2 + ks) * 512
                 + lane * 8) = v;
    }
}

// --------------------------------------------------------------------------
// Basis/silu expansion: XE[bc][yp][xp][8], SE[bc][yp][xp]; halo = p=0 values.
// --------------------------------------------------------------------------
__global__ __launch_bounds__(256)
void expand(const float* __restrict__ x, const float* __restrict__ grid,
            __bf16* __restrict__ xe, __bf16* __restrict__ se)
{
  const int idx = blockIdx.x * 256 + threadIdx.x;
  if (idx >= NEXP) return;
  const int xp = idx % NPAD;
  const int r  = idx / NPAD;
  const int yp = r % NPAD;
  const int bc = r / NPAD;

  float p = 0.f;
  if (xp >= 1 && xp <= HW_DIM && yp >= 1 && yp <= HW_DIM)
    p = x[(size_t)bc * (HW_DIM * HW_DIM) + (yp - 1) * HW_DIM + (xp - 1)];

  bf16x8 v;
#pragma unroll
  for (int g = 0; g < NG; ++g) {
    const float z = 1.75f * (p - grid[g]);
    v[g] = (__bf16)__expf(-z * z);
  }
  *(bf16x8*)(xe + (size_t)idx * NG) = v;
  const float e = __expf(-p);
  se[idx] = (__bf16)(p * __builtin_amdgcn_rcpf(1.f + e));
}

static __device__ __forceinline__ void gload16(const __bf16* g, __bf16* l) {
  __builtin_amdgcn_global_load_lds(
      (const __attribute__((address_space(1))) void*)g,
      (__attribute__((address_space(3))) void*)l, 16, 0, 0);
}

// counted-vmcnt barrier (T4): keep 5 newest VMEM ops in flight across it
#define WAITBAR5() do {                                      \
    asm volatile("s_waitcnt vmcnt(5)" ::: "memory");         \
    __builtin_amdgcn_s_barrier();                            \
    __builtin_amdgcn_sched_barrier(0);                       \
  } while (0)

// --------------------------------------------------------------------------
// GEMM: 1024 blocks (32px each) x 256 thr (4 waves of 32px x 32co)
// -> 4 blocks/CU, 4 waves/SIMD. Spline (72 steps): distance-2 pipeline,
// exactly 5 VMEM ops/thread/step (1 global_load_lds for the 4KB A-tile into
// a 3-deep LDS ring + 4 b128 B-frag loads into 3 named register sets);
// barrier = s_waitcnt vmcnt(5) + raw s_barrier (loads stay in flight).
// Base (9 steps): silu LDS gathers + __syncthreads.
// --------------------------------------------------------------------------
__global__ __launch_bounds__(256, 4)
void kan_gemm(const __bf16* __restrict__ xe, const __bf16* __restrict__ se,
              const __bf16* __restrict__ wt3, const float* __restrict__ base_b,
              float* __restrict__ out)
{
  __shared__ __align__(16) __bf16 As[3][BM][64];   // 3 x 4 KB ring
  __shared__ int tbl[576];                         // c*4356 + kh*66 + kw

  const int t    = threadIdx.x;
  const int lane = t & 63;
  const int wid  = t >> 6;              // 0..3 = co-quarter
  const int l15  = lane & 15;
  const int g4   = lane >> 4;

  // bijective XCD swizzle: 1024 blocks = 8 XCDs x 128 -> one image per XCD
  const int bid = blockIdx.x;
  const int swz = (bid & 7) * 128 + (bid >> 3);
  const int m0  = swz * BM;             // first pixel
  const int b   = m0 >> 12;             // image
  const int rem = m0 & 4095;
  const int y0  = rem >> 6;             // image row
  const int x0  = rem & 63;             // 0 or 32

  for (int f = t; f < 576; f += 256) {
    const int c  = f / 9;
    const int j  = f - 9 * c;
    const int kh = j / 3;
    const int kw = j - 3 * kh;
    tbl[f] = c * 4356 + kh * 66 + kw;
  }

  const int ROW = b * 278784 + y0 * 66;

  // A-staging: thread t -> slot (px = t>>3, gslot = t&7); slot holds feature
  // granule q = gslot ^ (px&7)  (G21 pre-swizzle at the global source).
  const int qsrc  = (t & 7) ^ ((t >> 3) & 7);
  const int pbase = x0 + (t >> 3);

  f32x4 acc[2][2];                      // [n co-16][m px-16]
#pragma unroll
  for (int n = 0; n < 2; ++n)
#pragma unroll
    for (int m = 0; m < 2; ++m)
      acc[n][m] = f32x4{0.f, 0.f, 0.f, 0.f};

  auto stageA = [&](int buf, int step) {
    const int off = ROW + tbl[step * 8 + qsrc] + pbase;
    gload16(xe + (size_t)off * 8, &As[buf][0][0] + t * 8);
  };

  auto loadB = [&](bf16x8 (&wf)[2][2], int step) {
    const __bf16* wb = wt3 + (size_t)step * 8192 + wid * 2048 + lane * 8;
#pragma unroll
    for (int n = 0; n < 2; ++n)
#pragma unroll
      for (int ks = 0; ks < 2; ++ks)
        wf[n][ks] = *(const bf16x8*)(wb + (n * 2 + ks) * 512);
  };

  auto compute = [&](int buf, bf16x8 (&wf)[2][2]) {
    bf16x8 xf[2][2];
#pragma unroll
    for (int ks = 0; ks < 2; ++ks)
#pragma unroll
      for (int m = 0; m < 2; ++m) {
        const int pr = m * 16 + l15;
        xf[m][ks] = *(const bf16x8*)(&As[buf][pr][(((ks * 4 + g4) ^ (pr & 7)) * 8)]);
      }
#pragma unroll
    for (int ks = 0; ks < 2; ++ks)
#pragma unroll
      for (int n = 0; n < 2; ++n)
#pragma unroll
        for (int m = 0; m < 2; ++m)
          acc[n][m] = __builtin_amdgcn_mfma_f32_16x16x32_bf16(
              wf[n][ks], xf[m][ks], acc[n][m], 0, 0, 0);
  };

  __syncthreads();                      // tbl ready

  // ---- spline phase: distance-2 pipeline, counted-vmcnt barriers ----
  bf16x8 wA[2][2], wB[2][2], wC[2][2];
  stageA(0, 0); loadB(wA, 0);           // 5 VMEM ops
  stageA(1, 1); loadB(wB, 1);           // 5 VMEM ops
  WAITBAR5();                           // step-0 landed; step-1 in flight

  for (int s = 0; s < 69; s += 3) {
    stageA(2, s + 2); loadB(wC, s + 2);
    compute(0, wA);
    WAITBAR5();
    stageA(0, s + 3); loadB(wA, s + 3);
    compute(1, wB);
    WAITBAR5();
    stageA(1, s + 4); loadB(wB, s + 4);
    compute(2, wC);
    WAITBAR5();
  }
  // steps 69..71 (A69/buf0, A70/buf1 already staged; stage 71 here)
  stageA(2, 71); loadB(wC, 71);
  compute(0, wA);                       // step 69
  WAITBAR5();                           // A(70) landed
  compute(1, wB);                       // step 70
  asm volatile("s_waitcnt vmcnt(0)" ::: "memory");
  __builtin_amdgcn_s_barrier();
  __builtin_amdgcn_sched_barrier(0);
  compute(2, wC);                       // step 71

  // ---- base phase: silu(p) patches via LDS (9 steps) ----
  auto stageBase = [&](int buf, int bs) {
    const int px    = t >> 3;
    const int gslot = t & 7;
    bf16x8 v;
#pragma unroll
    for (int jj = 0; jj < 8; ++jj) {
      const int f = (bs - NSPL_STEPS) * 64 + qsrc * 8 + jj;
      v[jj] = se[(size_t)(ROW + tbl[f] + pbase)];
    }
    *(bf16x8*)(&As[buf][px][gslot * 8]) = v;
  };

  stageBase(0, NSPL_STEPS);             // buf0 free (last compute used buf2)
  __syncthreads();
  for (int bs = NSPL_STEPS; bs < NSTEPS; ++bs) {
    const int cb = (bs - NSPL_STEPS) & 1;
    if (bs + 1 < NSTEPS) stageBase(cb ^ 1, bs + 1);
    loadB(wA, bs);
    compute(cb, wA);
    __syncthreads();
  }

  // ---- epilogue: D[co][pix]; l15 -> consecutive x: coalesced ----
#pragma unroll
  for (int n = 0; n < 2; ++n) {
    const int co = wid * 32 + n * 16 + g4 * 4;
#pragma unroll
    for (int m = 0; m < 2; ++m) {
      const int pl = m * 16 + l15;
      float* o = out + (size_t)(b * C_OUT + co) * 4096 + y0 * 64 + x0 + pl;
#pragma unroll
      for (int i = 0; i < 4; ++i)
        o[(size_t)i * 4096] = acc[n][m][i] + base_b[co + i];
    }
  }
}

extern "C" void kernel_launch(void* const* d_in, const int* in_sizes, int n_in,
                              void* d_out, int out_size, void* d_ws, size_t ws_size,
                              hipStream_t stream) {
  const float* x    = (const float*)d_in[0];
  const float* grid = (const float*)d_in[1];
  const float* sw   = (const float*)d_in[2];
  const float* bw   = (const float*)d_in[3];
  const float* bb   = (const float*)d_in[4];
  float* out = (float*)d_out;

  __bf16* wt3 = (__bf16*)d_ws;
  __bf16* xe  = (__bf16*)((char*)d_ws + XE_OFF);
  __bf16* se  = (__bf16*)((char*)d_ws + SE_OFF);

  prep_wt<<<NSTEPS, 256, 0, stream>>>(sw, bw, wt3);
  expand<<<(NEXP + 255) / 256, 256, 0, stream>>>(x, grid, xe, se);
  kan_gemm<<<1024, 256, 0, stream>>>(xe, se, wt3, bb, out);
}

// Round 13
// 87.984 us; speedup vs baseline: 1.2322x; 1.2322x over previous
//
#include <hip/hip_runtime.h>

#define C_IN   64
#define HW_DIM 64
#define C_OUT  128
#define NG     8
#define KSPL   4608     // 576 * 8
#define BM     64       // pixels per block = one image row
#define NIV    36       // spline intervals of BK=128
#define NBASE  9        // base steps of BK=64
#define NPAD   66
#define NEXP   (8 * C_IN * NPAD * NPAD)   // 2,230,272 padded elements

// wt3: spline 36*16384 + base 9*8192 elems
#define BOFF     589824                   // elem offset of base weights
#define WT_BYTES 1327104
#define XE_OFF   WT_BYTES
#define XE_BYTES (NEXP * NG * 2)          // 35,684,352
#define SE_OFF   (XE_OFF + XE_BYTES)

// granule swizzle: involution on low 3 bits
#define SW(c, p) (((c) & 8) | (((c) ^ (p)) & 7))

typedef __attribute__((ext_vector_type(8))) __bf16 bf16x8;
typedef __attribute__((ext_vector_type(4))) float  f32x4;

// --------------------------------------------------------------------------
// Weight prep. Spline blocks (0..35): wt3[iv][cq][n*4+ks][lane][8],
// co = cq*32+n*16+(lane&15), k = iv*128 + ks*32 + (lane>>4)*8 + e.
// Base blocks (36..44): wt3[BOFF + bs*8192 + cq*2048 + (n*2+ks)*512 + lane*8],
// k = 4608 + bs*64 + ks*32 + (lane>>4)*8 + e.
// --------------------------------------------------------------------------
__global__ __launch_bounds__(256)
void prep_wt(const float* __restrict__ sw, const float* __restrict__ bw,
             __bf16* __restrict__ wt3)
{
  const int bid  = blockIdx.x;
  const int t    = threadIdx.x;
  const int cq   = t >> 6;
  const int lane = t & 63;
  const int l15  = lane & 15;
  const int g4   = lane >> 4;
  if (bid < NIV) {                      // spline
    const int iv = bid;
#pragma unroll
    for (int n = 0; n < 2; ++n)
#pragma unroll
      for (int ks = 0; ks < 4; ++ks) {
        const int co = cq * 32 + n * 16 + l15;
        bf16x8 v;
#pragma unroll
        for (int e = 0; e < 8; ++e) {
          const int k = iv * 128 + ks * 32 + g4 * 8 + e;
          v[e] = (__bf16)sw[(size_t)k * C_OUT + co];
        }
        *(bf16x8*)(wt3 + (size_t)iv * 16384 + cq * 4096 + (n * 4 + ks) * 512
                   + lane * 8) = v;
      }
  } else {                              // base
    const int bs = bid - NIV;
#pragma unroll
    for (int n = 0; n < 2; ++n)
#pragma unroll
      for (int ks = 0; ks < 2; ++ks) {
        const int co = cq * 32 + n * 16 + l15;
        bf16x8 v;
#pragma unroll
        for (int e = 0; e < 8; ++e) {
          const int kb = bs * 64 + ks * 32 + g4 * 8 + e;
          v[e] = (__bf16)bw[(size_t)kb * C_OUT + co];
        }
        *(bf16x8*)(wt3 + (size_t)BOFF + bs * 8192 + cq * 2048 + (n * 2 + ks) * 512
                   + lane * 8) = v;
      }
  }
}

// --------------------------------------------------------------------------
// Basis/silu expansion: XE[bc][yp][xp][8], SE[bc][yp][xp]; halo = p=0 values.
// --------------------------------------------------------------------------
__global__ __launch_bounds__(256)
void expand(const float* __restrict__ x, const float* __restrict__ grid,
            __bf16* __restrict__ xe, __bf16* __restrict__ se)
{
  const int idx = blockIdx.x * 256 + threadIdx.x;
  if (idx >= NEXP) return;
  const int xp = idx % NPAD;
  const int r  = idx / NPAD;
  const int yp = r % NPAD;
  const int bc = r / NPAD;

  float p = 0.f;
  if (xp >= 1 && xp <= HW_DIM && yp >= 1 && yp <= HW_DIM)
    p = x[(size_t)bc * (HW_DIM * HW_DIM) + (yp - 1) * HW_DIM + (xp - 1)];

  bf16x8 v;
#pragma unroll
  for (int g = 0; g < NG; ++g) {
    const float z = 1.75f * (p - grid[g]);
    v[g] = (__bf16)__expf(-z * z);
  }
  *(bf16x8*)(xe + (size_t)idx * NG) = v;
  const float e = __expf(-p);
  se[idx] = (__bf16)(p * __builtin_amdgcn_rcpf(1.f + e));
}

static __device__ __forceinline__ void gload16(const __bf16* g, __bf16* l) {
  __builtin_amdgcn_global_load_lds(
      (const __attribute__((address_space(1))) void*)g,
      (__attribute__((address_space(3))) void*)l, 16, 0, 0);
}

// counted-vmcnt barrier (T4): keep 12 newest VMEM ops in flight across it
#define WAITBAR12() do {                                     \
    asm volatile("s_waitcnt vmcnt(12)" ::: "memory");        \
    __builtin_amdgcn_s_barrier();                            \
    __builtin_amdgcn_sched_barrier(0);                       \
  } while (0)

// --------------------------------------------------------------------------
// GEMM: 512 blocks (1 image row) x 4 waves (64px x 32co each).
// Spline: 36 intervals of BK=128, distance-2 ring, 12 VMEM ops/thread/interval
// (4 global_load_lds for the 16KB A-tile + 8 b128 B-frags into 3 named sets),
// barrier = s_waitcnt vmcnt(12) + raw s_barrier. Base: 9 BK=64 LDS steps.
// --------------------------------------------------------------------------
__global__ __launch_bounds__(256, 2)
void kan_gemm(const __bf16* __restrict__ xe, const __bf16* __restrict__ se,
              const __bf16* __restrict__ wt3, const float* __restrict__ base_b,
              float* __restrict__ out)
{
  __shared__ __align__(16) __bf16 AsF[3 * 64 * 128];   // 3 x 16 KB ring
  __shared__ int tbl[576];                             // c*4356 + kh*66 + kw

  const int t    = threadIdx.x;
  const int lane = t & 63;
  const int wid  = t >> 6;              // 0..3 = co-quarter
  const int l15  = lane & 15;
  const int g4   = lane >> 4;

  // bijective XCD swizzle: 512 blocks = 8 XCDs x 64 -> one image per XCD
  const int bid = blockIdx.x;
  const int swz = (bid & 7) * 64 + (bid >> 3);
  const int b   = swz >> 6;             // image
  const int y0  = swz & 63;             // image row

  for (int f = t; f < 576; f += 256) {
    const int c  = f / 9;
    const int j  = f - 9 * c;
    const int kh = j / 3;
    const int kw = j - 3 * kh;
    tbl[f] = c * 4356 + kh * 66 + kw;
  }

  const int ROW = b * 278784 + y0 * 66;

  f32x4 acc[2][4];
#pragma unroll
  for (int n = 0; n < 2; ++n)
#pragma unroll
    for (int m = 0; m < 4; ++m)
      acc[n][m] = f32x4{0.f, 0.f, 0.f, 0.f};

  // ---- spline A-stage: 4 gload16. Thread t owns slot (px, gslot) with
  // px = p*16 + (t>>4), gslot = t&15 -> elem = p*2048 + t*8 (16 rows x 128
  // elems per pass). Slot holds feature-granule SW(gslot,px) (G21). ----
  auto stageA = [&](int buf, int iv) {
    const int gslot = t & 15;
    __bf16* dst = AsF + buf * 8192 + t * 8;
#pragma unroll
    for (int p = 0; p < 4; ++p) {
      const int px  = p * 16 + (t >> 4);
      const int f   = iv * 16 + SW(gslot, px);
      const int off = ROW + tbl[f] + px;
      gload16(xe + (size_t)off * 8, dst + p * 2048);
    }
  };

  auto loadB = [&](bf16x8 (&wf)[2][4], int iv) {
    const __bf16* wb = wt3 + (size_t)iv * 16384 + wid * 4096 + lane * 8;
#pragma unroll
    for (int n = 0; n < 2; ++n)
#pragma unroll
      for (int ks = 0; ks < 4; ++ks)
        wf[n][ks] = *(const bf16x8*)(wb + (n * 4 + ks) * 512);
  };

  auto compute = [&](int buf, bf16x8 (&wf)[2][4]) {
    __builtin_amdgcn_s_setprio(1);
#pragma unroll
    for (int ks = 0; ks < 4; ++ks) {
      const int gidx = ks * 4 + g4;     // feature-granule 0..15
      bf16x8 xf[4];
#pragma unroll
      for (int m = 0; m < 4; ++m) {
        const int pr = m * 16 + l15;
        xf[m] = *(const bf16x8*)(AsF + buf * 8192 + pr * 128 + SW(gidx, pr) * 8);
      }
#pragma unroll
      for (int n = 0; n < 2; ++n)
#pragma unroll
        for (int m = 0; m < 4; ++m)
          acc[n][m] = __builtin_amdgcn_mfma_f32_16x16x32_bf16(
              wf[n][ks], xf[m], acc[n][m], 0, 0, 0);
    }
    __builtin_amdgcn_s_setprio(0);
  };

  __syncthreads();                      // tbl ready

  // ---- spline: 36 intervals, distance-2, counted-vmcnt barriers ----
  bf16x8 wA[2][4], wB[2][4], wC[2][4];
  stageA(0, 0); loadB(wA, 0);           // 12 VMEM ops
  stageA(1, 1); loadB(wB, 1);           // 12 VMEM ops
  WAITBAR12();                          // interval-0 landed; 1 in flight

  for (int s = 0; s < 33; s += 3) {
    stageA(2, s + 2); loadB(wC, s + 2);
    compute(0, wA);
    WAITBAR12();
    stageA(0, s + 3); loadB(wA, s + 3);
    compute(1, wB);
    WAITBAR12();
    stageA(1, s + 4); loadB(wB, s + 4);
    compute(2, wC);
    WAITBAR12();
  }
  // intervals 33..35 (33/buf0, 34/buf1 staged; stage 35 here)
  stageA(2, 35); loadB(wC, 35);
  compute(0, wA);                       // interval 33
  WAITBAR12();                          // 34 landed; 35 in flight
  compute(1, wB);                       // interval 34
  asm volatile("s_waitcnt vmcnt(0)" ::: "memory");
  __builtin_amdgcn_s_barrier();
  __builtin_amdgcn_sched_barrier(0);
  compute(2, wC);                       // interval 35

  // ---- base phase: silu(p) patches via LDS (9 BK=64 steps) ----
  // Coverage: 64 px x 8 granules via 2 slots/thread (r8-proven pattern).
  auto stageBase = [&](int buf, int bs) {
    const int px = t & 63;
#pragma unroll
    for (int h = 0; h < 2; ++h) {
      const int gslot = (t >> 6) + h * 4;   // 0..7
      const int q     = gslot ^ (px & 7);   // feature granule held by slot
      bf16x8 v;
#pragma unroll
      for (int jj = 0; jj < 8; ++jj) {
        const int f = bs * 64 + q * 8 + jj;
        v[jj] = se[(size_t)(ROW + tbl[f] + px)];
      }
      *(bf16x8*)(AsF + buf * 8192 + px * 64 + gslot * 8) = v;
    }
  };

  auto loadBbase = [&](bf16x8 (&wf)[2][2], int bs) {
    const __bf16* wb = wt3 + (size_t)BOFF + bs * 8192 + wid * 2048 + lane * 8;
#pragma unroll
    for (int n = 0; n < 2; ++n)
#pragma unroll
      for (int ks = 0; ks < 2; ++ks)
        wf[n][ks] = *(const bf16x8*)(wb + (n * 2 + ks) * 512);
  };

  auto computeBase = [&](int buf, bf16x8 (&wf)[2][2]) {
#pragma unroll
    for (int ks = 0; ks < 2; ++ks) {
      const int gidx = ks * 4 + g4;     // 0..7
      bf16x8 xf[4];
#pragma unroll
      for (int m = 0; m < 4; ++m) {
        const int pr = m * 16 + l15;
        xf[m] = *(const bf16x8*)(AsF + buf * 8192 + pr * 64
                                 + (gidx ^ (pr & 7)) * 8);
      }
#pragma unroll
      for (int n = 0; n < 2; ++n)
#pragma unroll
        for (int m = 0; m < 4; ++m)
          acc[n][m] = __builtin_amdgcn_mfma_f32_16x16x32_bf16(
              wf[n][ks], xf[m], acc[n][m], 0, 0, 0);
    }
  };

  stageBase(0, 0);                      // buf0 free (last compute used buf2)
  __syncthreads();
  bf16x8 wD[2][2];
  for (int bs = 0; bs < NBASE; ++bs) {
    const int cb = bs & 1;
    if (bs + 1 < NBASE) stageBase(cb ^ 1, bs + 1);
    loadBbase(wD, bs);
    computeBase(cb, wD);
    __syncthreads();
  }

  // ---- epilogue: D[co][pix]; l15 -> consecutive x: coalesced ----
#pragma unroll
  for (int n = 0; n < 2; ++n) {
    const int co = wid * 32 + n * 16 + g4 * 4;
#pragma unroll
    for (int m = 0; m < 4; ++m) {
      const int pl = m * 16 + l15;
      float* o = out + (size_t)(b * C_OUT + co) * 4096 + y0 * 64 + pl;
#pragma unroll
      for (int i = 0; i < 4; ++i)
        o[(size_t)i * 4096] = acc[n][m][i] + base_b[co + i];
    }
  }
}

extern "C" void kernel_launch(void* const* d_in, const int* in_sizes, int n_in,
                              void* d_out, int out_size, void* d_ws, size_t ws_size,
                              hipStream_t stream) {
  const float* x    = (const float*)d_in[0];
  const float* grid = (const float*)d_in[1];
  const float* sw   = (const float*)d_in[2];
  const float* bw   = (const float*)d_in[3];
  const float* bb   = (const float*)d_in[4];
  float* out = (float*)d_out;

  __bf16* wt3 = (__bf16*)d_ws;
  __bf16* xe  = (__bf16*)((char*)d_ws + XE_OFF);
  __bf16* se  = (__bf16*)((char*)d_ws + SE_OFF);

  prep_wt<<<NIV + NBASE, 256, 0, stream>>>(sw, bw, wt3);
  expand<<<(NEXP + 255) / 256, 256, 0, stream>>>(x, grid, xe, se);
  kan_gemm<<<512, 256, 0, stream>>>(xe, se, wt3, bb, out);
}